// Round 1
// 568.972 us; speedup vs baseline: 1.0099x; 1.0099x over previous
//
#include <hip/hip_runtime.h>
#include <stdint.h>

// Problem constants
#define S_LEN   2048
#define NH      12
#define NBH     24            // B*H
#define DMODEL  768
#define OUT0    3145728       // 4096*768  (output elements)
#define SD      131072        // 2048*64   (per-head elems)
#define WSZ     589824        // 768*768

// Workspace layout (in bf16/ushort elements)
#define QB_OFF   0
#define KB_OFF   3145728
#define VB_OFF   6291456
#define WQ_OFF   9437184
#define WK_OFF   10027008
#define WV_OFF   10616832
#define WO_OFF   11206656
#define QH_OFF   11796480     // Q  [bh][s][64]  (pre-scaled by 1/8)
#define KH_OFF   14942208     // K  [bh][s][64]
#define VT_OFF   18087936     // Vt [bh][64][s]
#define CTX_OFF  21233664     // ctx [b][s][h*64+d]  (== [4096][768])

typedef __attribute__((ext_vector_type(4))) float          f32x4;
typedef __attribute__((ext_vector_type(8))) __bf16         bf16x8;
typedef __attribute__((ext_vector_type(4))) __bf16         bf16x4;
typedef __attribute__((ext_vector_type(4))) float          fl4;
typedef __attribute__((ext_vector_type(4))) unsigned short us4;

__device__ __forceinline__ unsigned short f2bf(float f) {
  union { float f; unsigned u; } x; x.f = f;
  return (unsigned short)((x.u + 0x7FFFu + ((x.u >> 16) & 1u)) >> 16); // RNE
}

__device__ __forceinline__ float fexp2(float x) {
#if __has_builtin(__builtin_amdgcn_exp2f)
  return __builtin_amdgcn_exp2f(x);
#else
  return exp2f(x);
#endif
}

// async global->LDS, 16B per lane; lds base must be wave-uniform
__device__ __forceinline__ void gld16(const void* g, void* l) {
  __builtin_amdgcn_global_load_lds((__attribute__((address_space(1))) void*)g,
                                   (__attribute__((address_space(3))) void*)l,
                                   16, 0, 0);
}

#define MFMA(a, b, c) __builtin_amdgcn_mfma_f32_16x16x32_bf16((a), (b), (c), 0, 0, 0)
#define MEMBAR() asm volatile("" ::: "memory")
#define SBAR()   __builtin_amdgcn_s_barrier()

// ---------------- Kernel 1: fp32 -> bf16 conversion -----------------------
__global__ __launch_bounds__(256) void cvt_kernel(
    const float* __restrict__ q, const float* __restrict__ k, const float* __restrict__ v,
    const float* __restrict__ wq, const float* __restrict__ wk, const float* __restrict__ wv,
    const float* __restrict__ wo, unsigned short* __restrict__ ws)
{
  const int seg = blockIdx.y;
  const float* src; unsigned short* dst; int n; float sc = 1.0f;
  if      (seg == 0) { src = q;  dst = ws + QB_OFF; n = OUT0; }
  else if (seg == 1) { src = k;  dst = ws + KB_OFF; n = OUT0; }
  else if (seg == 2) { src = v;  dst = ws + VB_OFF; n = OUT0; }
  else if (seg == 3) { src = wq; dst = ws + WQ_OFF; n = WSZ; sc = 0.125f; } // fold 1/sqrt(64)
  else if (seg == 4) { src = wk; dst = ws + WK_OFF; n = WSZ; }
  else if (seg == 5) { src = wv; dst = ws + WV_OFF; n = WSZ; }
  else               { src = wo; dst = ws + WO_OFF; n = WSZ; }
  const int i4 = blockIdx.x * blockDim.x + threadIdx.x;
  if (i4 * 4 >= n) return;
  fl4 f = ((const fl4*)src)[i4];
  us4 o;
  o.x = f2bf(f.x * sc); o.y = f2bf(f.y * sc);
  o.z = f2bf(f.z * sc); o.w = f2bf(f.w * sc);
  ((us4*)dst)[i4] = o;
}

// ---------------- Kernel 2: fused QKV projection (BT GEMM) ----------------
// Y[m][n] = sum_k X[m][k] * W[n][k] + bias[n]
// LDS tiles are chunk-swizzled: global 16B chunk c of row r lands at LDS chunk
// c ^ (r&7) (linear gld16 dest + pre-swizzled per-lane SOURCE); all ds_reads
// XOR the same term -> 8 requests/bank (b128 optimum) instead of 16.
__global__ __launch_bounds__(256, 2) void proj_qkv(
    unsigned short* __restrict__ ws, const float* __restrict__ bq,
    const float* __restrict__ bk, const float* __restrict__ bv)
{
  __shared__ __align__(16) unsigned short As[2][8192];
  __shared__ __align__(16) unsigned short Bs[2][8192];
  const int mat = blockIdx.z;
  const unsigned short* X = ws + (size_t)mat * OUT0;
  const unsigned short* W = ws + WQ_OFF + (size_t)mat * WSZ;
  const float* bias = (mat == 0) ? bq : ((mat == 1) ? bk : bv);
  const float bsc = (mat == 0) ? 0.125f : 1.0f;
  unsigned short* dst = ws + QH_OFF + (size_t)mat * OUT0;
  const int m0 = blockIdx.y * 128, n0 = blockIdx.x * 128;
  const int tid = threadIdx.x, lane = tid & 63, w = tid >> 6;
  const int wm = w >> 1, wn = w & 1, qd = lane >> 4, ln = lane & 15;
  const int srow = lane >> 3, sc8 = ((lane & 7) ^ srow) * 8;  // swizzled source chunk

  // prologue: stage k-slice 0 into buf 0
#pragma unroll
  for (int i = 0; i < 4; i++) {
    const int row = (w * 4 + i) * 8 + srow;
    gld16(X + (size_t)(m0 + row) * 768 + sc8, &As[0][(w * 4 + i) * 512]);
    gld16(W + (size_t)(n0 + row) * 768 + sc8, &Bs[0][(w * 4 + i) * 512]);
  }

  f32x4 acc[4][4] = {};
  for (int kk = 0; kk < 12; kk++) {
    const int knx = (kk == 11) ? 0 : (kk + 1);   // wrap: harmless dummy prefetch on last iter
    const int nb = (kk + 1) & 1;
#pragma unroll
    for (int i = 0; i < 4; i++) {
      const int row = (w * 4 + i) * 8 + srow;
      gld16(X + (size_t)(m0 + row) * 768 + knx * 64 + sc8, &As[nb][(w * 4 + i) * 512]);
      gld16(W + (size_t)(n0 + row) * 768 + knx * 64 + sc8, &Bs[nb][(w * 4 + i) * 512]);
    }
    asm volatile("s_waitcnt vmcnt(8)" ::: "memory");  // current tile ready, next stays in flight
    SBAR();
    const unsigned short* Ac = As[kk & 1];
    const unsigned short* Bc = Bs[kk & 1];
    bf16x8 a[4][2], b[4][2];
#pragma unroll
    for (int kst = 0; kst < 2; kst++) {
#pragma unroll
      for (int mt = 0; mt < 4; mt++)
        a[mt][kst] = *(const bf16x8*)(Ac + (wm * 64 + mt * 16 + ln) * 64 + (((kst * 4 + qd) ^ (ln & 7)) * 8));
#pragma unroll
      for (int nt = 0; nt < 4; nt++)
        b[nt][kst] = *(const bf16x8*)(Bc + (wn * 64 + nt * 16 + ln) * 64 + (((kst * 4 + qd) ^ (ln & 7)) * 8));
    }
#pragma unroll
    for (int mt = 0; mt < 4; mt++)
#pragma unroll
      for (int nt = 0; nt < 4; nt++) {
        acc[mt][nt] = MFMA(a[mt][0], b[nt][0], acc[mt][nt]);
        acc[mt][nt] = MFMA(a[mt][1], b[nt][1], acc[mt][nt]);
      }
    MEMBAR();
    SBAR();
  }
#pragma unroll
  for (int nt = 0; nt < 4; nt++) {
    const int n = n0 + wn * 64 + nt * 16 + ln;
    const float bvv = bias[n] * bsc;
    const int h = n >> 6, d = n & 63;
    if (mat < 2) {
#pragma unroll
      for (int mt = 0; mt < 4; mt++)
#pragma unroll
        for (int r = 0; r < 4; r++) {
          const int m = m0 + wm * 64 + mt * 16 + qd * 4 + r;
          const int bb = m >> 11, s = m & 2047;
          dst[(size_t)(bb * NH + h) * SD + (size_t)s * 64 + d] = f2bf(acc[mt][nt][r] + bvv);
        }
    } else {
#pragma unroll
      for (int mt = 0; mt < 4; mt++) {
        const int m = m0 + wm * 64 + mt * 16 + qd * 4;
        const int bb = m >> 11, s = m & 2047;
        us4 o;
        o.x = f2bf(acc[mt][nt][0] + bvv); o.y = f2bf(acc[mt][nt][1] + bvv);
        o.z = f2bf(acc[mt][nt][2] + bvv); o.w = f2bf(acc[mt][nt][3] + bvv);
        *(us4*)(dst + (size_t)(bb * NH + h) * SD + (size_t)d * S_LEN + s) = o;
      }
    }
  }
  asm volatile("s_waitcnt vmcnt(0)" ::: "memory");  // drain dummy gld16 before endpgm (LDS teardown)
}

// ---------------- Kernel 3: attention --------------------------------------
// Swapped-operand QK^T: mfma(K_frag, Q_frag) -> lane holds S[k=..+qd*4+r][q=..+ln],
// i.e. 4 CONSECUTIVE k-columns per lane => dwordx4 attn stores, b64 P repack,
// shuffle-only row sums. K double-buffered, counted vmcnt (no full drains).
__global__ __launch_bounds__(256, 2) void attn_kernel(
    unsigned short* __restrict__ ws, float* __restrict__ attn_out)
{
  // 80 KB: K0 16K | K1 16K | Vt 16K | P 32K (rsum + Qs overlaid on P region)
  __shared__ __align__(16) unsigned short lds[40960];
  unsigned short* K0 = lds;                  // [128][64]  swizzled
  unsigned short* K1 = lds + 8192;           // [128][64]  swizzled
  unsigned short* Vt = lds + 16384;          // [64][128]  swizzled
  unsigned short* P  = lds + 24576;          // [128][128] bf16, xor-swizzled (sweep2)
  float* rsum        = (float*)(lds + 24576);// 128 f32 (sweep1 only, dead before P writes)
  unsigned short* Qs = lds + 32768;          // [128][64]  swizzled (pre-sweep only)

  const int bh = blockIdx.y;
  const int i0 = blockIdx.x * 128;
  const unsigned short* Qg = ws + QH_OFF + (size_t)bh * SD + (size_t)i0 * 64;
  const unsigned short* Kg = ws + KH_OFF + (size_t)bh * SD;
  const unsigned short* Vg = ws + VT_OFF + (size_t)bh * SD;   // [64][2048]
  float* attnB = attn_out + (size_t)bh * S_LEN * S_LEN + (size_t)i0 * S_LEN;
  unsigned short* ctxB = ws + CTX_OFF + ((size_t)(bh / NH) * S_LEN + i0) * DMODEL + (bh % NH) * 64;

  const int tid = threadIdx.x, lane = tid & 63, w = tid >> 6;
  const int wm = w >> 1, wn = w & 1, qd = lane >> 4, ln = lane & 15;
  const int srow = lane >> 3, sc8 = ((lane & 7) ^ srow) * 8;
  const float LOG2E = 1.4426950408889634f;

  // stage Q (swizzled source), then K(0) -> K0. Order matters for vmcnt FIFO.
#pragma unroll
  for (int i = 0; i < 4; i++) {
    const int row = (w * 4 + i) * 8 + srow;
    gld16(Qg + (size_t)row * 64 + sc8, Qs + (w * 4 + i) * 512);
  }
  MEMBAR();
#pragma unroll
  for (int i = 0; i < 4; i++) {
    const int row = (w * 4 + i) * 8 + srow;
    gld16(Kg + (size_t)row * 64 + sc8, K0 + (w * 4 + i) * 512);
  }
  if (tid < 128) rsum[tid] = 0.f;
  asm volatile("s_waitcnt vmcnt(4) lgkmcnt(0)" ::: "memory");  // Q ready; K(0) stays in flight
  SBAR();

  // Q fragments (B operand), loop-invariant
  bf16x8 bq[4][2];
#pragma unroll
  for (int kst = 0; kst < 2; kst++)
#pragma unroll
    for (int qt = 0; qt < 4; qt++)
      bq[qt][kst] = *(const bf16x8*)(Qs + (wm * 64 + qt * 16 + ln) * 64 + (((kst * 4 + qd) ^ (ln & 7)) * 8));

  // ---- sweep 1: row sums of exp(scores) ----
  float psl[4] = {0.f, 0.f, 0.f, 0.f};
  for (int jt = 0; jt < 16; jt++) {
    const unsigned short* Kn = Kg + (size_t)((jt + 1) & 15) * 8192;  // wrap: leaves K(0) staged for sweep2
    unsigned short* Kw = (jt & 1) ? K0 : K1;
#pragma unroll
    for (int i = 0; i < 4; i++) {
      const int row = (w * 4 + i) * 8 + srow;
      gld16(Kn + (size_t)row * 64 + sc8, Kw + (w * 4 + i) * 512);
    }
    asm volatile("s_waitcnt vmcnt(4)" ::: "memory");  // K(jt) ready; K(jt+1) in flight
    SBAR();
    const unsigned short* Kc = (jt & 1) ? K1 : K0;
    bf16x8 ak[4][2];
#pragma unroll
    for (int kst = 0; kst < 2; kst++)
#pragma unroll
      for (int kt = 0; kt < 4; kt++)
        ak[kt][kst] = *(const bf16x8*)(Kc + (wn * 64 + kt * 16 + ln) * 64 + (((kst * 4 + qd) ^ (ln & 7)) * 8));
#pragma unroll
    for (int qt = 0; qt < 4; qt++)
#pragma unroll
      for (int kt = 0; kt < 4; kt++) {
        f32x4 c = {0.f, 0.f, 0.f, 0.f};
        c = MFMA(ak[kt][0], bq[qt][0], c);
        c = MFMA(ak[kt][1], bq[qt][1], c);
        psl[qt] += fexp2(c[0] * LOG2E) + fexp2(c[1] * LOG2E)
                 + fexp2(c[2] * LOG2E) + fexp2(c[3] * LOG2E);
      }
    MEMBAR();
    SBAR();  // reads done before next overwrite
  }
  // reduce: qd-lanes (same q) via shuffles, wn-halves via 4 LDS atomics
#pragma unroll
  for (int qt = 0; qt < 4; qt++) {
    float v = psl[qt];
    v += __shfl_xor(v, 16);
    v += __shfl_xor(v, 32);
    psl[qt] = v;
  }
  if (lane < 16) {
#pragma unroll
    for (int qt = 0; qt < 4; qt++)
      atomicAdd(&rsum[wm * 64 + qt * 16 + lane], psl[qt]);
  }
  asm volatile("s_waitcnt lgkmcnt(0)" ::: "memory");
  SBAR();
  float rv[4];
#pragma unroll
  for (int qt = 0; qt < 4; qt++) rv[qt] = 1.0f / rsum[wm * 64 + qt * 16 + ln];

  // ---- sweep 2: normalized attn write + PV ----
  f32x4 ctx[4][2] = {};
  for (int jt = 0; jt < 16; jt++) {
    // issue V(jt) then K(jt+1): V must be OLDER in the vmcnt FIFO
#pragma unroll
    for (int i = 0; i < 4; i++) {
      const int d = (w * 4 + i) * 4 + qd;
      const int csw = ((lane & 15) ^ ((i & 1) * 4 + qd)) * 8;  // (lane&15) ^ (d&7)
      gld16(Vg + (size_t)d * S_LEN + jt * 128 + csw, Vt + (w * 4 + i) * 512);
    }
    MEMBAR();
    const unsigned short* Kn = Kg + (size_t)((jt + 1) & 15) * 8192;  // wrap dummy on last iter
    unsigned short* Kw = (jt & 1) ? K0 : K1;
#pragma unroll
    for (int i = 0; i < 4; i++) {
      const int row = (w * 4 + i) * 8 + srow;
      gld16(Kn + (size_t)row * 64 + sc8, Kw + (w * 4 + i) * 512);
    }
    // FIFO: [K(jt):4, st(jt-1):16, V(jt):4, K(jt+1):4] -> keep newest 8 => K(jt) retired
    asm volatile("s_waitcnt vmcnt(8)" ::: "memory");
    SBAR();

    const unsigned short* Kc = (jt & 1) ? K1 : K0;
    bf16x8 ak[4][2];
#pragma unroll
    for (int kst = 0; kst < 2; kst++)
#pragma unroll
      for (int kt = 0; kt < 4; kt++)
        ak[kt][kst] = *(const bf16x8*)(Kc + (wn * 64 + kt * 16 + ln) * 64 + (((kst * 4 + qd) ^ (ln & 7)) * 8));

#pragma unroll
    for (int qt = 0; qt < 4; qt++) {
      const int qrow = wm * 64 + qt * 16 + ln;
      float* aRow = attnB + (size_t)qrow * S_LEN + jt * 128 + wn * 64 + qd * 4;
      unsigned short* pRow = P + qrow * 128;
      const int r7x8 = (ln & 7) * 8;
#pragma unroll
      for (int kt = 0; kt < 4; kt++) {
        f32x4 c = {0.f, 0.f, 0.f, 0.f};
        c = MFMA(ak[kt][0], bq[qt][0], c);
        c = MFMA(ak[kt][1], bq[qt][1], c);
        f32x4 pv;
        pv.x = fexp2(c[0] * LOG2E) * rv[qt];
        pv.y = fexp2(c[1] * LOG2E) * rv[qt];
        pv.z = fexp2(c[2] * LOG2E) * rv[qt];
        pv.w = fexp2(c[3] * LOG2E) * rv[qt];
        *(f32x4*)(aRow + kt * 16) = pv;                       // 4 consecutive k-cols: dwordx4
        bf16x4 pb;
        pb.x = (__bf16)pv.x; pb.y = (__bf16)pv.y;
        pb.z = (__bf16)pv.z; pb.w = (__bf16)pv.w;
        *(bf16x4*)(pRow + ((wn * 64 + kt * 16 + qd * 4) ^ r7x8)) = pb;  // b64, xor-swizzled
      }
    }
    // FIFO: [V:4, K(jt+1):4, st(jt):16] = 24 -> <=20 retires V; K(jt+1)+stores stay in flight
    asm volatile("s_waitcnt vmcnt(20) lgkmcnt(0)" ::: "memory");
    SBAR();
    // PV: ctx[q-rows wm*64..][dims wn*32..] += P[128x128] @ V[128x64]
#pragma unroll
    for (int kst = 0; kst < 4; kst++) {
      bf16x8 pa[4], vb[2];
#pragma unroll
      for (int mt = 0; mt < 4; mt++)
        pa[mt] = *(const bf16x8*)(P + (wm * 64 + mt * 16 + ln) * 128 + ((kst * 32 + qd * 8) ^ ((ln & 7) * 8)));
#pragma unroll
      for (int nt = 0; nt < 2; nt++)
        vb[nt] = *(const bf16x8*)(Vt + (wn * 32 + nt * 16 + ln) * 128 + (((kst * 4 + qd) ^ (ln & 7)) * 8));
#pragma unroll
      for (int mt = 0; mt < 4; mt++)
#pragma unroll
        for (int nt = 0; nt < 2; nt++)
          ctx[mt][nt] = MFMA(pa[mt], vb[nt], ctx[mt][nt]);
    }
    MEMBAR();
    SBAR();  // P/Vt reads done before next iter's staging
  }
#pragma unroll
  for (int mt = 0; mt < 4; mt++)
#pragma unroll
    for (int nt = 0; nt < 2; nt++)
#pragma unroll
      for (int r = 0; r < 4; r++) {
        const int row = wm * 64 + mt * 16 + qd * 4 + r;
        ctxB[(size_t)row * DMODEL + wn * 32 + nt * 16 + ln] = f2bf(ctx[mt][nt][r]);
      }
  asm volatile("s_waitcnt vmcnt(0)" ::: "memory");  // drain dummy prefetch before endpgm
}

// ---------------- Kernel 4: output projection ------------------------------
__global__ __launch_bounds__(256, 2) void out_proj(
    const unsigned short* __restrict__ ws, const float* __restrict__ wob,
    float* __restrict__ out)
{
  __shared__ __align__(16) unsigned short As[2][8192];
  __shared__ __align__(16) unsigned short Bs[2][8192];
  const unsigned short* X = ws + CTX_OFF;
  const unsigned short* W = ws + WO_OFF;
  const int m0 = blockIdx.y * 128, n0 = blockIdx.x * 128;
  const int tid = threadIdx.x, lane = tid & 63, w = tid >> 6;
  const int wm = w >> 1, wn = w & 1, qd = lane >> 4, ln = lane & 15;
  const int srow = lane >> 3, sc8 = ((lane & 7) ^ srow) * 8;

#pragma unroll
  for (int i = 0; i < 4; i++) {
    const int row = (w * 4 + i) * 8 + srow;
    gld16(X + (size_t)(m0 + row) * 768 + sc8, &As[0][(w * 4 + i) * 512]);
    gld16(W + (size_t)(n0 + row) * 768 + sc8, &Bs[0][(w * 4 + i) * 512]);
  }

  f32x4 acc[4][4] = {};
  for (int kk = 0; kk < 12; kk++) {
    const int knx = (kk == 11) ? 0 : (kk + 1);
    const int nb = (kk + 1) & 1;
#pragma unroll
    for (int i = 0; i < 4; i++) {
      const int row = (w * 4 + i) * 8 + srow;
      gld16(X + (size_t)(m0 + row) * 768 + knx * 64 + sc8, &As[nb][(w * 4 + i) * 512]);
      gld16(W + (size_t)(n0 + row) * 768 + knx * 64 + sc8, &Bs[nb][(w * 4 + i) * 512]);
    }
    asm volatile("s_waitcnt vmcnt(8)" ::: "memory");
    SBAR();
    const unsigned short* Ac = As[kk & 1];
    const unsigned short* Bc = Bs[kk & 1];
    bf16x8 a[4][2], b[4][2];
#pragma unroll
    for (int kst = 0; kst < 2; kst++) {
#pragma unroll
      for (int mt = 0; mt < 4; mt++)
        a[mt][kst] = *(const bf16x8*)(Ac + (wm * 64 + mt * 16 + ln) * 64 + (((kst * 4 + qd) ^ (ln & 7)) * 8));
#pragma unroll
      for (int nt = 0; nt < 4; nt++)
        b[nt][kst] = *(const bf16x8*)(Bc + (wn * 64 + nt * 16 + ln) * 64 + (((kst * 4 + qd) ^ (ln & 7)) * 8));
    }
#pragma unroll
    for (int mt = 0; mt < 4; mt++)
#pragma unroll
      for (int nt = 0; nt < 4; nt++) {
        acc[mt][nt] = MFMA(a[mt][0], b[nt][0], acc[mt][nt]);
        acc[mt][nt] = MFMA(a[mt][1], b[nt][1], acc[mt][nt]);
      }
    MEMBAR();
    SBAR();
  }
#pragma unroll
  for (int nt = 0; nt < 4; nt++) {
    const int n = n0 + wn * 64 + nt * 16 + ln;
    const float bvv = wob[n];
#pragma unroll
    for (int mt = 0; mt < 4; mt++)
#pragma unroll
      for (int r = 0; r < 4; r++) {
        const int m = m0 + wm * 64 + mt * 16 + qd * 4 + r;
        out[(size_t)m * DMODEL + n] = acc[mt][nt][r] + bvv;
      }
  }
  asm volatile("s_waitcnt vmcnt(0)" ::: "memory");
}

// ---------------- launch ---------------------------------------------------
extern "C" void kernel_launch(void* const* d_in, const int* in_sizes, int n_in,
                              void* d_out, int out_size, void* d_ws, size_t ws_size,
                              hipStream_t stream)
{
  const float* q  = (const float*)d_in[0];
  const float* k  = (const float*)d_in[1];
  const float* v  = (const float*)d_in[2];
  const float* wq = (const float*)d_in[3];
  const float* bq = (const float*)d_in[4];
  const float* wk = (const float*)d_in[5];
  const float* bk = (const float*)d_in[6];
  const float* wv = (const float*)d_in[7];
  const float* bv = (const float*)d_in[8];
  const float* wo = (const float*)d_in[9];
  const float* bo = (const float*)d_in[10];
  unsigned short* ws = (unsigned short*)d_ws;
  float* out = (float*)d_out;

  cvt_kernel<<<dim3(3072, 7), 256, 0, stream>>>(q, k, v, wq, wk, wv, wo, ws);
  proj_qkv<<<dim3(6, 32, 3), 256, 0, stream>>>(ws, bq, bk, bv);
  attn_kernel<<<dim3(16, 24), 256, 0, stream>>>(ws, out + OUT0);
  out_proj<<<dim3(6, 32), 256, 0, stream>>>(ws, bo, out);
}

// Round 2
// 568.793 us; speedup vs baseline: 1.0102x; 1.0003x over previous
//
#include <hip/hip_runtime.h>
#include <stdint.h>

// Problem constants
#define S_LEN   2048
#define NH      12
#define NBH     24            // B*H
#define DMODEL  768
#define OUT0    3145728       // 4096*768  (output elements)
#define SD      131072        // 2048*64   (per-head elems)
#define WSZ     589824        // 768*768

// Workspace layout (in bf16/ushort elements)
#define QB_OFF   0
#define KB_OFF   3145728
#define VB_OFF   6291456
#define WQ_OFF   9437184
#define WK_OFF   10027008
#define WV_OFF   10616832
#define WO_OFF   11206656
#define QH_OFF   11796480     // Q  [bh][s][64]  (pre-scaled by 1/8)
#define KH_OFF   14942208     // K  [bh][s][64]
#define VT_OFF   18087936     // Vt [bh][64][s]
#define CTX_OFF  21233664     // ctx [b][s][h*64+d]  (== [4096][768])

typedef __attribute__((ext_vector_type(4))) float          f32x4;
typedef __attribute__((ext_vector_type(8))) __bf16         bf16x8;
typedef __attribute__((ext_vector_type(4))) float          fl4;
typedef __attribute__((ext_vector_type(4))) unsigned short us4;

__device__ __forceinline__ unsigned short f2bf(float f) {
  union { float f; unsigned u; } x; x.f = f;
  return (unsigned short)((x.u + 0x7FFFu + ((x.u >> 16) & 1u)) >> 16); // RNE
}

__device__ __forceinline__ float fexp2(float x) {
#if __has_builtin(__builtin_amdgcn_exp2f)
  return __builtin_amdgcn_exp2f(x);
#else
  return exp2f(x);
#endif
}

// async global->LDS, 16B per lane; lds base must be wave-uniform
__device__ __forceinline__ void gld16(const void* g, void* l) {
  __builtin_amdgcn_global_load_lds((__attribute__((address_space(1))) void*)g,
                                   (__attribute__((address_space(3))) void*)l,
                                   16, 0, 0);
}

#define MFMA(a, b, c) __builtin_amdgcn_mfma_f32_16x16x32_bf16((a), (b), (c), 0, 0, 0)
#define MEMBAR() asm volatile("" ::: "memory")
#define SBAR()   __builtin_amdgcn_s_barrier()

// ---------------- Kernel 1: fp32 -> bf16 conversion -----------------------
__global__ __launch_bounds__(256) void cvt_kernel(
    const float* __restrict__ q, const float* __restrict__ k, const float* __restrict__ v,
    const float* __restrict__ wq, const float* __restrict__ wk, const float* __restrict__ wv,
    const float* __restrict__ wo, unsigned short* __restrict__ ws)
{
  const int seg = blockIdx.y;
  const float* src; unsigned short* dst; int n; float sc = 1.0f;
  if      (seg == 0) { src = q;  dst = ws + QB_OFF; n = OUT0; }
  else if (seg == 1) { src = k;  dst = ws + KB_OFF; n = OUT0; }
  else if (seg == 2) { src = v;  dst = ws + VB_OFF; n = OUT0; }
  else if (seg == 3) { src = wq; dst = ws + WQ_OFF; n = WSZ; sc = 0.125f; } // fold 1/sqrt(64)
  else if (seg == 4) { src = wk; dst = ws + WK_OFF; n = WSZ; }
  else if (seg == 5) { src = wv; dst = ws + WV_OFF; n = WSZ; }
  else               { src = wo; dst = ws + WO_OFF; n = WSZ; }
  const int i4 = blockIdx.x * blockDim.x + threadIdx.x;
  if (i4 * 4 >= n) return;
  fl4 f = ((const fl4*)src)[i4];
  us4 o;
  o.x = f2bf(f.x * sc); o.y = f2bf(f.y * sc);
  o.z = f2bf(f.z * sc); o.w = f2bf(f.w * sc);
  ((us4*)dst)[i4] = o;
}

// ---------------- Kernel 2: fused QKV projection (BT GEMM) ----------------
__global__ __launch_bounds__(256, 2) void proj_qkv(
    unsigned short* __restrict__ ws, const float* __restrict__ bq,
    const float* __restrict__ bk, const float* __restrict__ bv)
{
  __shared__ __align__(16) unsigned short As[2][8192];
  __shared__ __align__(16) unsigned short Bs[2][8192];
  const int mat = blockIdx.z;
  const unsigned short* X = ws + (size_t)mat * OUT0;
  const unsigned short* W = ws + WQ_OFF + (size_t)mat * WSZ;
  const float* bias = (mat == 0) ? bq : ((mat == 1) ? bk : bv);
  const float bsc = (mat == 0) ? 0.125f : 1.0f;
  unsigned short* dst = ws + QH_OFF + (size_t)mat * OUT0;
  const int m0 = blockIdx.y * 128, n0 = blockIdx.x * 128;
  const int tid = threadIdx.x, lane = tid & 63, w = tid >> 6;
  const int wm = w >> 1, wn = w & 1, qd = lane >> 4, ln = lane & 15;
  const int srow = lane >> 3, sc8 = ((lane & 7) ^ srow) * 8;  // swizzled source chunk

#pragma unroll
  for (int i = 0; i < 4; i++) {
    const int row = (w * 4 + i) * 8 + srow;
    gld16(X + (size_t)(m0 + row) * 768 + sc8, &As[0][(w * 4 + i) * 512]);
    gld16(W + (size_t)(n0 + row) * 768 + sc8, &Bs[0][(w * 4 + i) * 512]);
  }

  f32x4 acc[4][4] = {};
  for (int kk = 0; kk < 12; kk++) {
    const int knx = (kk == 11) ? 0 : (kk + 1);   // wrap: harmless dummy prefetch on last iter
    const int nb = (kk + 1) & 1;
#pragma unroll
    for (int i = 0; i < 4; i++) {
      const int row = (w * 4 + i) * 8 + srow;
      gld16(X + (size_t)(m0 + row) * 768 + knx * 64 + sc8, &As[nb][(w * 4 + i) * 512]);
      gld16(W + (size_t)(n0 + row) * 768 + knx * 64 + sc8, &Bs[nb][(w * 4 + i) * 512]);
    }
    asm volatile("s_waitcnt vmcnt(8)" ::: "memory");  // current tile ready, next stays in flight
    SBAR();
    const unsigned short* Ac = As[kk & 1];
    const unsigned short* Bc = Bs[kk & 1];
    bf16x8 a[4][2], b[4][2];
#pragma unroll
    for (int kst = 0; kst < 2; kst++) {
#pragma unroll
      for (int mt = 0; mt < 4; mt++)
        a[mt][kst] = *(const bf16x8*)(Ac + (wm * 64 + mt * 16 + ln) * 64 + (((kst * 4 + qd) ^ (ln & 7)) * 8));
#pragma unroll
      for (int nt = 0; nt < 4; nt++)
        b[nt][kst] = *(const bf16x8*)(Bc + (wn * 64 + nt * 16 + ln) * 64 + (((kst * 4 + qd) ^ (ln & 7)) * 8));
    }
#pragma unroll
    for (int mt = 0; mt < 4; mt++)
#pragma unroll
      for (int nt = 0; nt < 4; nt++) {
        acc[mt][nt] = MFMA(a[mt][0], b[nt][0], acc[mt][nt]);
        acc[mt][nt] = MFMA(a[mt][1], b[nt][1], acc[mt][nt]);
      }
    MEMBAR();
    SBAR();
  }
#pragma unroll
  for (int nt = 0; nt < 4; nt++) {
    const int n = n0 + wn * 64 + nt * 16 + ln;
    const float bvv = bias[n] * bsc;
    const int h = n >> 6, d = n & 63;
    if (mat < 2) {
#pragma unroll
      for (int mt = 0; mt < 4; mt++)
#pragma unroll
        for (int r = 0; r < 4; r++) {
          const int m = m0 + wm * 64 + mt * 16 + qd * 4 + r;
          const int bb = m >> 11, s = m & 2047;
          dst[(size_t)(bb * NH + h) * SD + (size_t)s * 64 + d] = f2bf(acc[mt][nt][r] + bvv);
        }
    } else {
#pragma unroll
      for (int mt = 0; mt < 4; mt++) {
        const int m = m0 + wm * 64 + mt * 16 + qd * 4;
        const int bb = m >> 11, s = m & 2047;
        us4 o;
        o.x = f2bf(acc[mt][nt][0] + bvv); o.y = f2bf(acc[mt][nt][1] + bvv);
        o.z = f2bf(acc[mt][nt][2] + bvv); o.w = f2bf(acc[mt][nt][3] + bvv);
        *(us4*)(dst + (size_t)(bb * NH + h) * SD + (size_t)d * S_LEN + s) = o;
      }
    }
  }
  asm volatile("s_waitcnt vmcnt(0)" ::: "memory");  // drain dummy gld16 before endpgm
}

// ---------------- Kernel 3: attention --------------------------------------
// Strip = 64 q-rows, grid 32x24 = 768 blocks = exactly 3/CU (48 KB LDS).
// Each wave owns 16 q-rows x ALL 128 k-cols per tile:
//  - swapped QK^T (mfma(K,Q)) -> lane holds 4 consecutive k per (kt) frag
//  - rowsum is wave-local (2 shfl_xor, no LDS, no atomics)
//  - P repacked to PV A-fragments fully in-register (shfl), no P LDS, no barrier
// K double-buffered, V single-buffered (Q overlaid on V region pre-sweep).
__global__ __launch_bounds__(256, 3) void attn_kernel(
    unsigned short* __restrict__ ws, float* __restrict__ attn_out)
{
  // 48 KB: K0 16K | K1 16K | Vt 16K (Q staged into Vt before sweep 1)
  __shared__ __align__(16) unsigned short lds[24576];
  unsigned short* K0 = lds;                  // [128][64] swizzled
  unsigned short* K1 = lds + 8192;           // [128][64] swizzled
  unsigned short* Vt = lds + 16384;          // [64][128] swizzled / Q [64][64] pre-sweep

  const int bh = blockIdx.y;
  const int i0 = blockIdx.x * 64;
  const unsigned short* Qg = ws + QH_OFF + (size_t)bh * SD + (size_t)i0 * 64;
  const unsigned short* Kg = ws + KH_OFF + (size_t)bh * SD;
  const unsigned short* Vg = ws + VT_OFF + (size_t)bh * SD;   // [64][2048]
  float* attnB = attn_out + (size_t)bh * S_LEN * S_LEN + (size_t)i0 * S_LEN;
  unsigned short* ctxB = ws + CTX_OFF + ((size_t)(bh / NH) * S_LEN + i0) * DMODEL + (bh % NH) * 64;

  const int tid = threadIdx.x, lane = tid & 63, w = tid >> 6;
  const int qd = lane >> 4, ln = lane & 15;
  const int srow = lane >> 3, sc8 = ((lane & 7) ^ srow) * 8;
  const float LOG2E = 1.4426950408889634f;

  // ---- prologue: stage Q (into Vt region) then K(0)->K0 ----
#pragma unroll
  for (int i = 0; i < 2; i++) {
    const int row = (w * 2 + i) * 8 + srow;
    gld16(Qg + (size_t)row * 64 + sc8, Vt + (w * 2 + i) * 512);
  }
  MEMBAR();
#pragma unroll
  for (int i = 0; i < 4; i++) {
    const int row = (w * 4 + i) * 8 + srow;
    gld16(Kg + (size_t)row * 64 + sc8, K0 + (w * 4 + i) * 512);
  }
  asm volatile("s_waitcnt vmcnt(4)" ::: "memory");  // Q ready; K(0) in flight
  SBAR();

  // Q B-fragments (16 q-rows per wave), loop-invariant
  bf16x8 bq[2];
#pragma unroll
  for (int kst = 0; kst < 2; kst++)
    bq[kst] = *(const bf16x8*)(Vt + (w * 16 + ln) * 64 + (((kst * 4 + qd) ^ (ln & 7)) * 8));

  // ---- sweep 1: row sums of exp(scores) ----
  float psl = 0.f;
  for (int jt = 0; jt < 16; jt++) {
    const unsigned short* Kn = Kg + (size_t)((jt + 1) & 15) * 8192;  // wrap leaves K(0) in K0
    unsigned short* Kw = ((jt + 1) & 1) ? K1 : K0;
#pragma unroll
    for (int i = 0; i < 4; i++) {
      const int row = (w * 4 + i) * 8 + srow;
      gld16(Kn + (size_t)row * 64 + sc8, Kw + (w * 4 + i) * 512);
    }
    asm volatile("s_waitcnt vmcnt(4)" ::: "memory");  // K(jt) ready; K(jt+1) in flight
    SBAR();
    const unsigned short* Kc = (jt & 1) ? K1 : K0;
#pragma unroll
    for (int kt = 0; kt < 8; kt++) {
      bf16x8 ak0 = *(const bf16x8*)(Kc + (kt * 16 + ln) * 64 + ((qd ^ (ln & 7)) * 8));
      bf16x8 ak1 = *(const bf16x8*)(Kc + (kt * 16 + ln) * 64 + (((4 + qd) ^ (ln & 7)) * 8));
      f32x4 c = {0.f, 0.f, 0.f, 0.f};
      c = MFMA(ak0, bq[0], c);
      c = MFMA(ak1, bq[1], c);
      psl += fexp2(c[0] * LOG2E) + fexp2(c[1] * LOG2E)
           + fexp2(c[2] * LOG2E) + fexp2(c[3] * LOG2E);
    }
    MEMBAR();
    SBAR();  // all reads done before next overwrite
  }
  // wave-local rowsum: sum across the 4 qd groups (same q = ln)
  psl += __shfl_xor(psl, 16);
  psl += __shfl_xor(psl, 32);
  const float rv = 1.0f / psl;

  // lane indices for the in-register P repack
  const int l0 = ((qd & 1) * 2) * 16 + ln;   // source lane for k-elems j=0..3
  const int l1 = l0 + 16;                    // source lane for k-elems j=4..7
  const bool hi = (qd & 2) != 0;             // qd>=2 -> odd kt of the kst pair

  // ---- sweep 2: normalized attn write + PV ----
  f32x4 ctx[4] = {};
  for (int jt = 0; jt < 16; jt++) {
    // issue V(jt) (older) then K(jt+1) (newer)
#pragma unroll
    for (int i = 0; i < 4; i++) {
      const int d = (w * 4 + i) * 4 + qd;
      const int csw = ((lane & 15) ^ ((i & 1) * 4 + qd)) * 8;  // (lane&15) ^ (d&7)
      gld16(Vg + (size_t)d * S_LEN + jt * 128 + csw, Vt + (w * 4 + i) * 512);
    }
    MEMBAR();
    const unsigned short* Kn = Kg + (size_t)((jt + 1) & 15) * 8192;  // wrap dummy on last iter
    unsigned short* Kw = ((jt + 1) & 1) ? K1 : K0;
#pragma unroll
    for (int i = 0; i < 4; i++) {
      const int row = (w * 4 + i) * 8 + srow;
      gld16(Kn + (size_t)row * 64 + sc8, Kw + (w * 4 + i) * 512);
    }
    // FIFO: [K(jt):4, st(jt-1):8, V(jt):4, K(jt+1):4]=20 -> <=8 retires K(jt)+stores
    asm volatile("s_waitcnt vmcnt(8)" ::: "memory");
    SBAR();

    const unsigned short* Kc = (jt & 1) ? K1 : K0;
    unsigned pkx[8], pky[8];
#pragma unroll
    for (int kt = 0; kt < 8; kt++) {
      bf16x8 ak0 = *(const bf16x8*)(Kc + (kt * 16 + ln) * 64 + ((qd ^ (ln & 7)) * 8));
      bf16x8 ak1 = *(const bf16x8*)(Kc + (kt * 16 + ln) * 64 + (((4 + qd) ^ (ln & 7)) * 8));
      f32x4 c = {0.f, 0.f, 0.f, 0.f};
      c = MFMA(ak0, bq[0], c);
      c = MFMA(ak1, bq[1], c);
      f32x4 pv;
      pv.x = fexp2(c[0] * LOG2E) * rv;
      pv.y = fexp2(c[1] * LOG2E) * rv;
      pv.z = fexp2(c[2] * LOG2E) * rv;
      pv.w = fexp2(c[3] * LOG2E) * rv;
      // 4 consecutive k-cols per lane: one dwordx4 store
      *(f32x4*)(attnB + (size_t)(w * 16 + ln) * S_LEN + jt * 128 + kt * 16 + qd * 4) = pv;
      pkx[kt] = (unsigned)f2bf(pv.x) | ((unsigned)f2bf(pv.y) << 16);
      pky[kt] = (unsigned)f2bf(pv.z) | ((unsigned)f2bf(pv.w) << 16);
    }
    // FIFO: [V(jt):4, K(jt+1):4, st(jt):8]=16 -> <=12 retires V(jt)
    asm volatile("s_waitcnt vmcnt(12)" ::: "memory");
    SBAR();

    // PV: ctx[q 16 rows][d 0..63] += P[16x128] @ V[128x64], P from registers
#pragma unroll
    for (int kst = 0; kst < 4; kst++) {
      const int kA = kst * 2, kB = kst * 2 + 1;
      const int t0a = __shfl((int)pkx[kA], l0), t1a = __shfl((int)pky[kA], l0);
      const int t2a = __shfl((int)pkx[kA], l1), t3a = __shfl((int)pky[kA], l1);
      const int t0b = __shfl((int)pkx[kB], l0), t1b = __shfl((int)pky[kB], l0);
      const int t2b = __shfl((int)pkx[kB], l1), t3b = __shfl((int)pky[kB], l1);
      union { int u[4]; bf16x8 v; } pw;
      pw.u[0] = hi ? t0b : t0a; pw.u[1] = hi ? t1b : t1a;
      pw.u[2] = hi ? t2b : t2a; pw.u[3] = hi ? t3b : t3a;
#pragma unroll
      for (int nt = 0; nt < 4; nt++) {
        bf16x8 vb = *(const bf16x8*)(Vt + (nt * 16 + ln) * 128 + (((kst * 4 + qd) ^ (ln & 7)) * 8));
        ctx[nt] = MFMA(pw.v, vb, ctx[nt]);
      }
    }
    MEMBAR();
    SBAR();  // Vt reads done before next iter's staging
  }
#pragma unroll
  for (int nt = 0; nt < 4; nt++)
#pragma unroll
    for (int r = 0; r < 4; r++) {
      const int row = w * 16 + qd * 4 + r;
      ctxB[(size_t)row * DMODEL + nt * 16 + ln] = f2bf(ctx[nt][r]);
    }
  asm volatile("s_waitcnt vmcnt(0)" ::: "memory");  // drain dummy prefetch before endpgm
}

// ---------------- Kernel 4: output projection ------------------------------
__global__ __launch_bounds__(256, 2) void out_proj(
    const unsigned short* __restrict__ ws, const float* __restrict__ wob,
    float* __restrict__ out)
{
  __shared__ __align__(16) unsigned short As[2][8192];
  __shared__ __align__(16) unsigned short Bs[2][8192];
  const unsigned short* X = ws + CTX_OFF;
  const unsigned short* W = ws + WO_OFF;
  const int m0 = blockIdx.y * 128, n0 = blockIdx.x * 128;
  const int tid = threadIdx.x, lane = tid & 63, w = tid >> 6;
  const int wm = w >> 1, wn = w & 1, qd = lane >> 4, ln = lane & 15;
  const int srow = lane >> 3, sc8 = ((lane & 7) ^ srow) * 8;

#pragma unroll
  for (int i = 0; i < 4; i++) {
    const int row = (w * 4 + i) * 8 + srow;
    gld16(X + (size_t)(m0 + row) * 768 + sc8, &As[0][(w * 4 + i) * 512]);
    gld16(W + (size_t)(n0 + row) * 768 + sc8, &Bs[0][(w * 4 + i) * 512]);
  }

  f32x4 acc[4][4] = {};
  for (int kk = 0; kk < 12; kk++) {
    const int knx = (kk == 11) ? 0 : (kk + 1);
    const int nb = (kk + 1) & 1;
#pragma unroll
    for (int i = 0; i < 4; i++) {
      const int row = (w * 4 + i) * 8 + srow;
      gld16(X + (size_t)(m0 + row) * 768 + knx * 64 + sc8, &As[nb][(w * 4 + i) * 512]);
      gld16(W + (size_t)(n0 + row) * 768 + knx * 64 + sc8, &Bs[nb][(w * 4 + i) * 512]);
    }
    asm volatile("s_waitcnt vmcnt(8)" ::: "memory");
    SBAR();
    const unsigned short* Ac = As[kk & 1];
    const unsigned short* Bc = Bs[kk & 1];
    bf16x8 a[4][2], b[4][2];
#pragma unroll
    for (int kst = 0; kst < 2; kst++) {
#pragma unroll
      for (int mt = 0; mt < 4; mt++)
        a[mt][kst] = *(const bf16x8*)(Ac + (wm * 64 + mt * 16 + ln) * 64 + (((kst * 4 + qd) ^ (ln & 7)) * 8));
#pragma unroll
      for (int nt = 0; nt < 4; nt++)
        b[nt][kst] = *(const bf16x8*)(Bc + (wn * 64 + nt * 16 + ln) * 64 + (((kst * 4 + qd) ^ (ln & 7)) * 8));
    }
#pragma unroll
    for (int mt = 0; mt < 4; mt++)
#pragma unroll
      for (int nt = 0; nt < 4; nt++) {
        acc[mt][nt] = MFMA(a[mt][0], b[nt][0], acc[mt][nt]);
        acc[mt][nt] = MFMA(a[mt][1], b[nt][1], acc[mt][nt]);
      }
    MEMBAR();
    SBAR();
  }
#pragma unroll
  for (int nt = 0; nt < 4; nt++) {
    const int n = n0 + wn * 64 + nt * 16 + ln;
    const float bvv = wob[n];
#pragma unroll
    for (int mt = 0; mt < 4; mt++)
#pragma unroll
      for (int r = 0; r < 4; r++) {
        const int m = m0 + wm * 64 + mt * 16 + qd * 4 + r;
        out[(size_t)m * DMODEL + n] = acc[mt][nt][r] + bvv;
      }
  }
  asm volatile("s_waitcnt vmcnt(0)" ::: "memory");
}

// ---------------- launch ---------------------------------------------------
extern "C" void kernel_launch(void* const* d_in, const int* in_sizes, int n_in,
                              void* d_out, int out_size, void* d_ws, size_t ws_size,
                              hipStream_t stream)
{
  const float* q  = (const float*)d_in[0];
  const float* k  = (const float*)d_in[1];
  const float* v  = (const float*)d_in[2];
  const float* wq = (const float*)d_in[3];
  const float* bq = (const float*)d_in[4];
  const float* wk = (const float*)d_in[5];
  const float* bk = (const float*)d_in[6];
  const float* wv = (const float*)d_in[7];
  const float* bv = (const float*)d_in[8];
  const float* wo = (const float*)d_in[9];
  const float* bo = (const float*)d_in[10];
  unsigned short* ws = (unsigned short*)d_ws;
  float* out = (float*)d_out;

  cvt_kernel<<<dim3(3072, 7), 256, 0, stream>>>(q, k, v, wq, wk, wv, wo, ws);
  proj_qkv<<<dim3(6, 32, 3), 256, 0, stream>>>(ws, bq, bk, bv);
  attn_kernel<<<dim3(32, 24), 256, 0, stream>>>(ws, out + OUT0);
  out_proj<<<dim3(6, 32), 256, 0, stream>>>(ws, bo, out);
}

// Round 3
// 559.949 us; speedup vs baseline: 1.0262x; 1.0158x over previous
//
#include <hip/hip_runtime.h>
#include <stdint.h>

// Problem constants
#define S_LEN   2048
#define NH      12
#define NBH     24            // B*H
#define DMODEL  768
#define OUT0    3145728       // 4096*768  (output elements)
#define SD      131072        // 2048*64   (per-head elems)
#define WSZ     589824        // 768*768

// Workspace layout (in bf16/ushort elements)
#define QB_OFF   0
#define KB_OFF   3145728
#define VB_OFF   6291456
#define WQ_OFF   9437184
#define WK_OFF   10027008
#define WV_OFF   10616832
#define WO_OFF   11206656
#define QH_OFF   11796480     // Q  [bh][s][64]  (pre-scaled by 1/8)
#define KH_OFF   14942208     // K  [bh][s][64]
#define VT_OFF   18087936     // Vt [bh][64][s]
#define CTX_OFF  21233664     // ctx [b][s][h*64+d]  (== [4096][768])

typedef __attribute__((ext_vector_type(4))) float          f32x4;
typedef __attribute__((ext_vector_type(8))) __bf16         bf16x8;
typedef __attribute__((ext_vector_type(4))) float          fl4;
typedef __attribute__((ext_vector_type(4))) unsigned short us4;

__device__ __forceinline__ unsigned short f2bf(float f) {
  union { float f; unsigned u; } x; x.f = f;
  return (unsigned short)((x.u + 0x7FFFu + ((x.u >> 16) & 1u)) >> 16); // RNE
}

__device__ __forceinline__ float fexp2(float x) {
#if __has_builtin(__builtin_amdgcn_exp2f)
  return __builtin_amdgcn_exp2f(x);
#else
  return exp2f(x);
#endif
}

// async global->LDS, 16B per lane; lds base must be wave-uniform
__device__ __forceinline__ void gld16(const void* g, void* l) {
  __builtin_amdgcn_global_load_lds((__attribute__((address_space(1))) void*)g,
                                   (__attribute__((address_space(3))) void*)l,
                                   16, 0, 0);
}

#define MFMA(a, b, c) __builtin_amdgcn_mfma_f32_16x16x32_bf16((a), (b), (c), 0, 0, 0)
#define MEMBAR() asm volatile("" ::: "memory")
#define SBAR()   __builtin_amdgcn_s_barrier()

// ---------------- Kernel 1: fp32 -> bf16 conversion -----------------------
__global__ __launch_bounds__(256) void cvt_kernel(
    const float* __restrict__ q, const float* __restrict__ k, const float* __restrict__ v,
    const float* __restrict__ wq, const float* __restrict__ wk, const float* __restrict__ wv,
    const float* __restrict__ wo, unsigned short* __restrict__ ws)
{
  const int seg = blockIdx.y;
  const float* src; unsigned short* dst; int n; float sc = 1.0f;
  if      (seg == 0) { src = q;  dst = ws + QB_OFF; n = OUT0; }
  else if (seg == 1) { src = k;  dst = ws + KB_OFF; n = OUT0; }
  else if (seg == 2) { src = v;  dst = ws + VB_OFF; n = OUT0; }
  else if (seg == 3) { src = wq; dst = ws + WQ_OFF; n = WSZ; sc = 0.125f; } // fold 1/sqrt(64)
  else if (seg == 4) { src = wk; dst = ws + WK_OFF; n = WSZ; }
  else if (seg == 5) { src = wv; dst = ws + WV_OFF; n = WSZ; }
  else               { src = wo; dst = ws + WO_OFF; n = WSZ; }
  const int i4 = blockIdx.x * blockDim.x + threadIdx.x;
  if (i4 * 4 >= n) return;
  fl4 f = ((const fl4*)src)[i4];
  us4 o;
  o.x = f2bf(f.x * sc); o.y = f2bf(f.y * sc);
  o.z = f2bf(f.z * sc); o.w = f2bf(f.w * sc);
  ((us4*)dst)[i4] = o;
}

// ---------------- Kernel 2: fused QKV projection (BT GEMM) ----------------
__global__ __launch_bounds__(256, 2) void proj_qkv(
    unsigned short* __restrict__ ws, const float* __restrict__ bq,
    const float* __restrict__ bk, const float* __restrict__ bv)
{
  __shared__ __align__(16) unsigned short As[2][8192];
  __shared__ __align__(16) unsigned short Bs[2][8192];
  const int mat = blockIdx.z;
  const unsigned short* X = ws + (size_t)mat * OUT0;
  const unsigned short* W = ws + WQ_OFF + (size_t)mat * WSZ;
  const float* bias = (mat == 0) ? bq : ((mat == 1) ? bk : bv);
  const float bsc = (mat == 0) ? 0.125f : 1.0f;
  unsigned short* dst = ws + QH_OFF + (size_t)mat * OUT0;
  const int m0 = blockIdx.y * 128, n0 = blockIdx.x * 128;
  const int tid = threadIdx.x, lane = tid & 63, w = tid >> 6;
  const int wm = w >> 1, wn = w & 1, qd = lane >> 4, ln = lane & 15;
  const int srow = lane >> 3, sc8 = ((lane & 7) ^ srow) * 8;  // swizzled source chunk

#pragma unroll
  for (int i = 0; i < 4; i++) {
    const int row = (w * 4 + i) * 8 + srow;
    gld16(X + (size_t)(m0 + row) * 768 + sc8, &As[0][(w * 4 + i) * 512]);
    gld16(W + (size_t)(n0 + row) * 768 + sc8, &Bs[0][(w * 4 + i) * 512]);
  }

  f32x4 acc[4][4] = {};
  for (int kk = 0; kk < 12; kk++) {
    const int knx = (kk == 11) ? 0 : (kk + 1);   // wrap: harmless dummy prefetch on last iter
    const int nb = (kk + 1) & 1;
#pragma unroll
    for (int i = 0; i < 4; i++) {
      const int row = (w * 4 + i) * 8 + srow;
      gld16(X + (size_t)(m0 + row) * 768 + knx * 64 + sc8, &As[nb][(w * 4 + i) * 512]);
      gld16(W + (size_t)(n0 + row) * 768 + knx * 64 + sc8, &Bs[nb][(w * 4 + i) * 512]);
    }
    asm volatile("s_waitcnt vmcnt(8)" ::: "memory");  // current tile ready, next stays in flight
    SBAR();
    const unsigned short* Ac = As[kk & 1];
    const unsigned short* Bc = Bs[kk & 1];
    bf16x8 a[4][2], b[4][2];
#pragma unroll
    for (int kst = 0; kst < 2; kst++) {
#pragma unroll
      for (int mt = 0; mt < 4; mt++)
        a[mt][kst] = *(const bf16x8*)(Ac + (wm * 64 + mt * 16 + ln) * 64 + (((kst * 4 + qd) ^ (ln & 7)) * 8));
#pragma unroll
      for (int nt = 0; nt < 4; nt++)
        b[nt][kst] = *(const bf16x8*)(Bc + (wn * 64 + nt * 16 + ln) * 64 + (((kst * 4 + qd) ^ (ln & 7)) * 8));
    }
#pragma unroll
    for (int mt = 0; mt < 4; mt++)
#pragma unroll
      for (int nt = 0; nt < 4; nt++) {
        acc[mt][nt] = MFMA(a[mt][0], b[nt][0], acc[mt][nt]);
        acc[mt][nt] = MFMA(a[mt][1], b[nt][1], acc[mt][nt]);
      }
    MEMBAR();
    SBAR();
  }
#pragma unroll
  for (int nt = 0; nt < 4; nt++) {
    const int n = n0 + wn * 64 + nt * 16 + ln;
    const float bvv = bias[n] * bsc;
    const int h = n >> 6, d = n & 63;
    if (mat < 2) {
#pragma unroll
      for (int mt = 0; mt < 4; mt++)
#pragma unroll
        for (int r = 0; r < 4; r++) {
          const int m = m0 + wm * 64 + mt * 16 + qd * 4 + r;
          const int bb = m >> 11, s = m & 2047;
          dst[(size_t)(bb * NH + h) * SD + (size_t)s * 64 + d] = f2bf(acc[mt][nt][r] + bvv);
        }
    } else {
#pragma unroll
      for (int mt = 0; mt < 4; mt++) {
        const int m = m0 + wm * 64 + mt * 16 + qd * 4;
        const int bb = m >> 11, s = m & 2047;
        us4 o;
        o.x = f2bf(acc[mt][nt][0] + bvv); o.y = f2bf(acc[mt][nt][1] + bvv);
        o.z = f2bf(acc[mt][nt][2] + bvv); o.w = f2bf(acc[mt][nt][3] + bvv);
        *(us4*)(dst + (size_t)(bb * NH + h) * SD + (size_t)d * S_LEN + s) = o;
      }
    }
  }
  asm volatile("s_waitcnt vmcnt(0)" ::: "memory");  // drain dummy gld16 before endpgm
}

// ---------------- Kernel 3: attention --------------------------------------
// Strip = 64 q-rows; flattened grid of 768 with XCD-clustered head decode:
// xcd = bid&7 owns heads 3*xcd..3*xcd+2 -> per-XCD K/V working set = 1.5 MB
// (L2-resident) instead of 12 MB (thrash). Attn-weight stores are NON-TEMPORAL
// so the 402 MB write stream doesn't evict K/V from L2.
// Each wave owns 16 q-rows x all 128 k-cols; P repack fully in-register.
__global__ __launch_bounds__(256, 3) void attn_kernel(
    unsigned short* __restrict__ ws, float* __restrict__ attn_out)
{
  // 48 KB: K0 16K | K1 16K | Vt 16K (Q staged into Vt before sweep 1)
  __shared__ __align__(16) unsigned short lds[24576];
  unsigned short* K0 = lds;                  // [128][64] swizzled
  unsigned short* K1 = lds + 8192;           // [128][64] swizzled
  unsigned short* Vt = lds + 16384;          // [64][128] swizzled / Q [64][64] pre-sweep

  // XCD-clustered decode: dispatch round-robins blockIdx.x % 8 across XCDs.
  const int bid = blockIdx.x;
  const int xcd = bid & 7, idx = bid >> 3;   // idx 0..95
  const int bh = xcd * 3 + (idx >> 5);       // 3 heads per XCD
  const int i0 = (idx & 31) * 64;            // 32 strips per head

  const unsigned short* Qg = ws + QH_OFF + (size_t)bh * SD + (size_t)i0 * 64;
  const unsigned short* Kg = ws + KH_OFF + (size_t)bh * SD;
  const unsigned short* Vg = ws + VT_OFF + (size_t)bh * SD;   // [64][2048]
  float* attnB = attn_out + (size_t)bh * S_LEN * S_LEN + (size_t)i0 * S_LEN;
  unsigned short* ctxB = ws + CTX_OFF + ((size_t)(bh / NH) * S_LEN + i0) * DMODEL + (bh % NH) * 64;

  const int tid = threadIdx.x, lane = tid & 63, w = tid >> 6;
  const int qd = lane >> 4, ln = lane & 15;
  const int srow = lane >> 3, sc8 = ((lane & 7) ^ srow) * 8;
  const float LOG2E = 1.4426950408889634f;

  // ---- prologue: stage Q (into Vt region) then K(0)->K0 ----
#pragma unroll
  for (int i = 0; i < 2; i++) {
    const int row = (w * 2 + i) * 8 + srow;
    gld16(Qg + (size_t)row * 64 + sc8, Vt + (w * 2 + i) * 512);
  }
  MEMBAR();
#pragma unroll
  for (int i = 0; i < 4; i++) {
    const int row = (w * 4 + i) * 8 + srow;
    gld16(Kg + (size_t)row * 64 + sc8, K0 + (w * 4 + i) * 512);
  }
  asm volatile("s_waitcnt vmcnt(4)" ::: "memory");  // Q ready; K(0) in flight
  SBAR();

  // Q B-fragments (16 q-rows per wave), loop-invariant
  bf16x8 bq[2];
#pragma unroll
  for (int kst = 0; kst < 2; kst++)
    bq[kst] = *(const bf16x8*)(Vt + (w * 16 + ln) * 64 + (((kst * 4 + qd) ^ (ln & 7)) * 8));

  // ---- sweep 1: row sums of exp(scores) ----
  float psl = 0.f;
  for (int jt = 0; jt < 16; jt++) {
    const unsigned short* Kn = Kg + (size_t)((jt + 1) & 15) * 8192;  // wrap leaves K(0) in K0
    unsigned short* Kw = ((jt + 1) & 1) ? K1 : K0;
#pragma unroll
    for (int i = 0; i < 4; i++) {
      const int row = (w * 4 + i) * 8 + srow;
      gld16(Kn + (size_t)row * 64 + sc8, Kw + (w * 4 + i) * 512);
    }
    asm volatile("s_waitcnt vmcnt(4)" ::: "memory");  // K(jt) ready; K(jt+1) in flight
    SBAR();
    const unsigned short* Kc = (jt & 1) ? K1 : K0;
#pragma unroll
    for (int kt = 0; kt < 8; kt++) {
      bf16x8 ak0 = *(const bf16x8*)(Kc + (kt * 16 + ln) * 64 + ((qd ^ (ln & 7)) * 8));
      bf16x8 ak1 = *(const bf16x8*)(Kc + (kt * 16 + ln) * 64 + (((4 + qd) ^ (ln & 7)) * 8));
      f32x4 c = {0.f, 0.f, 0.f, 0.f};
      c = MFMA(ak0, bq[0], c);
      c = MFMA(ak1, bq[1], c);
      psl += fexp2(c[0] * LOG2E) + fexp2(c[1] * LOG2E)
           + fexp2(c[2] * LOG2E) + fexp2(c[3] * LOG2E);
    }
    MEMBAR();
    SBAR();  // all reads done before next overwrite
  }
  // wave-local rowsum: sum across the 4 qd groups (same q = ln)
  psl += __shfl_xor(psl, 16);
  psl += __shfl_xor(psl, 32);
  const float rv = 1.0f / psl;

  // lane indices for the in-register P repack
  const int l0 = ((qd & 1) * 2) * 16 + ln;   // source lane for k-elems j=0..3
  const int l1 = l0 + 16;                    // source lane for k-elems j=4..7
  const bool hi = (qd & 2) != 0;             // qd>=2 -> odd kt of the kst pair

  // ---- sweep 2: normalized attn write + PV ----
  f32x4 ctx[4] = {};
  for (int jt = 0; jt < 16; jt++) {
    // issue V(jt) (older) then K(jt+1) (newer)
#pragma unroll
    for (int i = 0; i < 4; i++) {
      const int d = (w * 4 + i) * 4 + qd;
      const int csw = ((lane & 15) ^ ((i & 1) * 4 + qd)) * 8;  // (lane&15) ^ (d&7)
      gld16(Vg + (size_t)d * S_LEN + jt * 128 + csw, Vt + (w * 4 + i) * 512);
    }
    MEMBAR();
    const unsigned short* Kn = Kg + (size_t)((jt + 1) & 15) * 8192;  // wrap dummy on last iter
    unsigned short* Kw = ((jt + 1) & 1) ? K1 : K0;
#pragma unroll
    for (int i = 0; i < 4; i++) {
      const int row = (w * 4 + i) * 8 + srow;
      gld16(Kn + (size_t)row * 64 + sc8, Kw + (w * 4 + i) * 512);
    }
    // FIFO: [K(jt):4, st(jt-1):8, V(jt):4, K(jt+1):4]=20 -> <=8 retires K(jt)+stores
    asm volatile("s_waitcnt vmcnt(8)" ::: "memory");
    SBAR();

    const unsigned short* Kc = (jt & 1) ? K1 : K0;
    unsigned pkx[8], pky[8];
#pragma unroll
    for (int kt = 0; kt < 8; kt++) {
      bf16x8 ak0 = *(const bf16x8*)(Kc + (kt * 16 + ln) * 64 + ((qd ^ (ln & 7)) * 8));
      bf16x8 ak1 = *(const bf16x8*)(Kc + (kt * 16 + ln) * 64 + (((4 + qd) ^ (ln & 7)) * 8));
      f32x4 c = {0.f, 0.f, 0.f, 0.f};
      c = MFMA(ak0, bq[0], c);
      c = MFMA(ak1, bq[1], c);
      f32x4 pv;
      pv.x = fexp2(c[0] * LOG2E) * rv;
      pv.y = fexp2(c[1] * LOG2E) * rv;
      pv.z = fexp2(c[2] * LOG2E) * rv;
      pv.w = fexp2(c[3] * LOG2E) * rv;
      // 4 consecutive k-cols per lane: one dwordx4 store, NON-TEMPORAL
      __builtin_nontemporal_store(pv,
        (f32x4*)(attnB + (size_t)(w * 16 + ln) * S_LEN + jt * 128 + kt * 16 + qd * 4));
      pkx[kt] = (unsigned)f2bf(pv.x) | ((unsigned)f2bf(pv.y) << 16);
      pky[kt] = (unsigned)f2bf(pv.z) | ((unsigned)f2bf(pv.w) << 16);
    }
    // FIFO: [V(jt):4, K(jt+1):4, st(jt):8]=16 -> <=12 retires V(jt)
    asm volatile("s_waitcnt vmcnt(12)" ::: "memory");
    SBAR();

    // PV: ctx[q 16 rows][d 0..63] += P[16x128] @ V[128x64], P from registers
#pragma unroll
    for (int kst = 0; kst < 4; kst++) {
      const int kA = kst * 2, kB = kst * 2 + 1;
      const int t0a = __shfl((int)pkx[kA], l0), t1a = __shfl((int)pky[kA], l0);
      const int t2a = __shfl((int)pkx[kA], l1), t3a = __shfl((int)pky[kA], l1);
      const int t0b = __shfl((int)pkx[kB], l0), t1b = __shfl((int)pky[kB], l0);
      const int t2b = __shfl((int)pkx[kB], l1), t3b = __shfl((int)pky[kB], l1);
      union { int u[4]; bf16x8 v; } pw;
      pw.u[0] = hi ? t0b : t0a; pw.u[1] = hi ? t1b : t1a;
      pw.u[2] = hi ? t2b : t2a; pw.u[3] = hi ? t3b : t3a;
#pragma unroll
      for (int nt = 0; nt < 4; nt++) {
        bf16x8 vb = *(const bf16x8*)(Vt + (nt * 16 + ln) * 128 + (((kst * 4 + qd) ^ (ln & 7)) * 8));
        ctx[nt] = MFMA(pw.v, vb, ctx[nt]);
      }
    }
    MEMBAR();
    SBAR();  // Vt reads done before next iter's staging
  }
#pragma unroll
  for (int nt = 0; nt < 4; nt++)
#pragma unroll
    for (int r = 0; r < 4; r++) {
      const int row = w * 16 + qd * 4 + r;
      ctxB[(size_t)row * DMODEL + nt * 16 + ln] = f2bf(ctx[nt][r]);
    }
  asm volatile("s_waitcnt vmcnt(0)" ::: "memory");  // drain dummy prefetch before endpgm
}

// ---------------- Kernel 4: output projection ------------------------------
__global__ __launch_bounds__(256, 2) void out_proj(
    const unsigned short* __restrict__ ws, const float* __restrict__ wob,
    float* __restrict__ out)
{
  __shared__ __align__(16) unsigned short As[2][8192];
  __shared__ __align__(16) unsigned short Bs[2][8192];
  const unsigned short* X = ws + CTX_OFF;
  const unsigned short* W = ws + WO_OFF;
  const int m0 = blockIdx.y * 128, n0 = blockIdx.x * 128;
  const int tid = threadIdx.x, lane = tid & 63, w = tid >> 6;
  const int wm = w >> 1, wn = w & 1, qd = lane >> 4, ln = lane & 15;
  const int srow = lane >> 3, sc8 = ((lane & 7) ^ srow) * 8;

#pragma unroll
  for (int i = 0; i < 4; i++) {
    const int row = (w * 4 + i) * 8 + srow;
    gld16(X + (size_t)(m0 + row) * 768 + sc8, &As[0][(w * 4 + i) * 512]);
    gld16(W + (size_t)(n0 + row) * 768 + sc8, &Bs[0][(w * 4 + i) * 512]);
  }

  f32x4 acc[4][4] = {};
  for (int kk = 0; kk < 12; kk++) {
    const int knx = (kk == 11) ? 0 : (kk + 1);
    const int nb = (kk + 1) & 1;
#pragma unroll
    for (int i = 0; i < 4; i++) {
      const int row = (w * 4 + i) * 8 + srow;
      gld16(X + (size_t)(m0 + row) * 768 + knx * 64 + sc8, &As[nb][(w * 4 + i) * 512]);
      gld16(W + (size_t)(n0 + row) * 768 + knx * 64 + sc8, &Bs[nb][(w * 4 + i) * 512]);
    }
    asm volatile("s_waitcnt vmcnt(8)" ::: "memory");
    SBAR();
    const unsigned short* Ac = As[kk & 1];
    const unsigned short* Bc = Bs[kk & 1];
    bf16x8 a[4][2], b[4][2];
#pragma unroll
    for (int kst = 0; kst < 2; kst++) {
#pragma unroll
      for (int mt = 0; mt < 4; mt++)
        a[mt][kst] = *(const bf16x8*)(Ac + (wm * 64 + mt * 16 + ln) * 64 + (((kst * 4 + qd) ^ (ln & 7)) * 8));
#pragma unroll
      for (int nt = 0; nt < 4; nt++)
        b[nt][kst] = *(const bf16x8*)(Bc + (wn * 64 + nt * 16 + ln) * 64 + (((kst * 4 + qd) ^ (ln & 7)) * 8));
    }
#pragma unroll
    for (int mt = 0; mt < 4; mt++)
#pragma unroll
      for (int nt = 0; nt < 4; nt++) {
        acc[mt][nt] = MFMA(a[mt][0], b[nt][0], acc[mt][nt]);
        acc[mt][nt] = MFMA(a[mt][1], b[nt][1], acc[mt][nt]);
      }
    MEMBAR();
    SBAR();
  }
#pragma unroll
  for (int nt = 0; nt < 4; nt++) {
    const int n = n0 + wn * 64 + nt * 16 + ln;
    const float bvv = wob[n];
#pragma unroll
    for (int mt = 0; mt < 4; mt++)
#pragma unroll
      for (int r = 0; r < 4; r++) {
        const int m = m0 + wm * 64 + mt * 16 + qd * 4 + r;
        out[(size_t)m * DMODEL + n] = acc[mt][nt][r] + bvv;
      }
  }
  asm volatile("s_waitcnt vmcnt(0)" ::: "memory");
}

// ---------------- launch ---------------------------------------------------
extern "C" void kernel_launch(void* const* d_in, const int* in_sizes, int n_in,
                              void* d_out, int out_size, void* d_ws, size_t ws_size,
                              hipStream_t stream)
{
  const float* q  = (const float*)d_in[0];
  const float* k  = (const float*)d_in[1];
  const float* v  = (const float*)d_in[2];
  const float* wq = (const float*)d_in[3];
  const float* bq = (const float*)d_in[4];
  const float* wk = (const float*)d_in[5];
  const float* bk = (const float*)d_in[6];
  const float* wv = (const float*)d_in[7];
  const float* bv = (const float*)d_in[8];
  const float* wo = (const float*)d_in[9];
  const float* bo = (const float*)d_in[10];
  unsigned short* ws = (unsigned short*)d_ws;
  float* out = (float*)d_out;

  cvt_kernel<<<dim3(3072, 7), 256, 0, stream>>>(q, k, v, wq, wk, wv, wo, ws);
  proj_qkv<<<dim3(6, 32, 3), 256, 0, stream>>>(ws, bq, bk, bv);
  attn_kernel<<<dim3(768), 256, 0, stream>>>(ws, out + OUT0);
  out_proj<<<dim3(6, 32), 256, 0, stream>>>(ws, bo, out);
}